// Round 2
// baseline (577.334 us; speedup 1.0000x reference)
//
#include <hip/hip_runtime.h>
#include <hip/hip_bf16.h>

// Bahdanau attention, restructured:
//   tanh_in[b,t,k] = e[b,t,:]@(U@Wa) + cvec[b,k]   (one 131072x512x512 bf16 GEMM)
//   cij[b,t] = sum_k tanh(tanh_in)*V[k]            (fused epilogue, no [B,T,H] tensor)
//   alphas = softmax(cij); out = sum_t alphas*e
// Shapes: B=32 T=4096 D=512 H=512.
//
// R5: (a) GEMM k-loop double-buffered (As 2x16KB + Bs 2x64KB = 160KB LDS, the
// gfx950 workgroup max). Per step: issue A(t+1) f4 loads + B(t+1) gload_lds
// FIRST, then MFMA on buffer t (hides HBM/L2 latency), then pack+ds_write
// A(t+1), then ONE __syncthreads (its vmcnt(0) drain lands after the MFMA
// cover). R4's structure exposed full load latency every step at 1 block/CU.
// (b) cij via in-LDS 4-way reduce, no atomics -> memset dropped (6 dispatches).
// (c) dens1+cvec fused into one direct-write kernel (no atomics).
// (d) softmax pass replaced by per-b (max, 1/sum) stats kernel; k_wsum computes
// alphas inline (saves a full 1MB pass + launch) and writes the alphas output.
// (e) k_wsum traversal REVERSED so it starts on the L3-resident tail of e.

#define BB 32
#define TT 4096
#define DD 512
#define HH 512
#define BK 64

typedef short s16x8 __attribute__((ext_vector_type(8)));
typedef float f32x4 __attribute__((ext_vector_type(4)));

union FU { float f; unsigned u; };

static __device__ __forceinline__ unsigned pack_bf16_trunc(float a, float b) {
    FU ua, ub; ua.f = a; ub.f = b;
    return (ua.u >> 16) | (ub.u & 0xffff0000u);
}

static __device__ __forceinline__ unsigned short f2bf_rne(float x) {
    FU v; v.f = x;
    unsigned u = v.u;
    u = u + 0x7fffu + ((u >> 16) & 1u);
    return (unsigned short)(u >> 16);
}

static __device__ __forceinline__ float tanh_fast(float x) {
    float e = __expf(2.0f * x);
    return 1.0f - 2.0f * __builtin_amdgcn_rcpf(e + 1.0f);
}

// async global->LDS, 16B/lane. LDS dest = wave-uniform base + lane*16.
static __device__ __forceinline__ void gload_lds16(const void* g, void* l) {
    __builtin_amdgcn_global_load_lds(
        (const __attribute__((address_space(1))) unsigned int*)g,
        (__attribute__((address_space(3))) unsigned int*)l, 16, 0, 0);
}

// ---------------------------------------------------------------------------
// A1+A2 fused: g = hs@W + bias (kept in LDS), cvec = g@Wa + ba (direct store).
// One block per batch row; no atomics, no memset dependency.
__global__ void k_head(const float* __restrict__ hs, const float* __restrict__ W,
                       const float* __restrict__ bias, const float* __restrict__ Wa,
                       const float* __restrict__ ba, float* __restrict__ cvec) {
    int b = blockIdx.x, tid = threadIdx.x;
    __shared__ float hss[DD];
    __shared__ float gs[HH];
    if (tid < 128)
        ((float4*)hss)[tid] = ((const float4*)(hs + (size_t)b * DD))[tid];
    __syncthreads();
    float a0 = bias[tid], a1 = bias[tid + 256];
    #pragma unroll 8
    for (int d = 0; d < DD; ++d) {
        float x = hss[d];
        a0 = fmaf(x, W[(size_t)d * HH + tid], a0);
        a1 = fmaf(x, W[(size_t)d * HH + 256 + tid], a1);
    }
    gs[tid] = a0;
    gs[tid + 256] = a1;
    __syncthreads();
    float c0 = ba[tid], c1 = ba[tid + 256];
    #pragma unroll 8
    for (int h = 0; h < HH; ++h) {
        float x = gs[h];
        c0 = fmaf(x, Wa[(size_t)h * HH + tid], c0);
        c1 = fmaf(x, Wa[(size_t)h * HH + 256 + tid], c1);
    }
    cvec[(size_t)b * HH + tid] = c0;
    cvec[(size_t)b * HH + 256 + tid] = c1;
}

// A3: UWaT[n][d] = bf16( sum_h U[d,h]*Wa[h,n] ) -- transposed for B-fragments.
__global__ void k_uwa(const float* __restrict__ U, const float* __restrict__ Wa,
                      unsigned short* __restrict__ UWaT) {
    int d0 = blockIdx.x * 8;
    int tid = threadIdx.x;
    __shared__ float Us[8][DD];
    #pragma unroll
    for (int i = 0; i < 16; ++i) {
        int idx = i * 256 + tid;
        Us[idx >> 9][idx & 511] = U[(size_t)(d0 + (idx >> 9)) * HH + (idx & 511)];
    }
    __syncthreads();
    float acc[8][2] = {};
    #pragma unroll 2
    for (int h = 0; h < DD; ++h) {
        float w0 = Wa[(size_t)h * HH + tid];
        float w1 = Wa[(size_t)h * HH + 256 + tid];
        #pragma unroll
        for (int dd = 0; dd < 8; ++dd) {
            float u = Us[dd][h];
            acc[dd][0] = fmaf(u, w0, acc[dd][0]);
            acc[dd][1] = fmaf(u, w1, acc[dd][1]);
        }
    }
    #pragma unroll
    for (int dd = 0; dd < 8; ++dd) {
        UWaT[(size_t)tid * DD + d0 + dd] = f2bf_rne(acc[dd][0]);
        UWaT[(size_t)(tid + 256) * DD + d0 + dd] = f2bf_rne(acc[dd][1]);
    }
}

// ---------------------------------------------------------------------------
// B: GEMM tile 128(M) x 512(N full), BK=64, DOUBLE-BUFFERED (As/Bs x2 = 160KB).
// 8 waves (2x4): wave (wr,wc) owns rows [wr*64,+64) x cols [wc*128,+128).
// Per step t: issue A(t+1) float4 loads + B(t+1) gload_lds into buf[nxt];
// MFMA on buf[cur]; pack+ds_write A(t+1); ONE __syncthreads (vmcnt drain is
// after the MFMA cover). e rows fetched EXACTLY once (43us HBM floor).
// LDS 16B-unit layouts (verified conflict-free in R2/R3):
//   Bs unit = col*8 + (g ^ (col&7)) ; As unit = g*128 + (row ^ g)
// Staging lane map (lane = rl*8+gg): src chunk = gg^rl -> LDS unit n0*8+lane.
// Epilogue: per-wave partials reduced in LDS (reusing As space) -> direct
// cij store, no atomics.
__global__ void __launch_bounds__(512, 2) k_gemm_tanh(
    const float* __restrict__ e, const unsigned short* __restrict__ Bt,
    const float* __restrict__ cvec, const float* __restrict__ V,
    float* __restrict__ cij) {
    int tid = threadIdx.x;
    int m0 = blockIdx.x * 128;         // 1024 blocks
    int lane = tid & 63, w = tid >> 6;
    int wr = w >> 2, wc = w & 3;
    int wm = wr * 64, wn = wc * 128;
    int lcol = lane & 15, q = lane >> 4;
    int rl = lane >> 3, gg = lane & 7;           // staging lane decomposition

    __shared__ __align__(16) unsigned short As[2][128 * BK];   // 2 x 16 KB
    __shared__ __align__(16) unsigned short Bs[2][512 * BK];   // 2 x 64 KB

    f32x4 acc[4][8] = {};
    const float* Abase = e + (size_t)m0 * DD;

    // ---- prologue: stage k-tile 0 into buffer 0
    {
        float4 av[4];
        #pragma unroll
        for (int it = 0; it < 4; ++it) {
            int idx = it * 512 + tid;
            int row = idx >> 4, c4 = idx & 15;
            av[it] = *(const float4*)(Abase + (size_t)row * DD + c4 * 4);
        }
        #pragma unroll
        for (int u = 0; u < 8; ++u) {
            int n0 = w * 64 + u * 8;
            gload_lds16(Bt + (size_t)(n0 + rl) * DD + ((gg ^ rl) << 3),
                        &Bs[0][n0 * 64]);
        }
        #pragma unroll
        for (int it = 0; it < 4; ++it) {
            int idx = it * 512 + tid;
            int row = idx >> 4, c4 = idx & 15;
            uint2 wv;
            wv.x = pack_bf16_trunc(av[it].x, av[it].y);
            wv.y = pack_bf16_trunc(av[it].z, av[it].w);
            int g = c4 >> 1, half = c4 & 1;
            *(uint2*)&As[0][(g * 128 + (row ^ g)) * 8 + half * 4] = wv;
        }
        __syncthreads();
    }

    for (int t = 0; t < 8; ++t) {
        unsigned short* AsC = As[t & 1];
        unsigned short* BsC = Bs[t & 1];
        unsigned short* AsN = As[(t & 1) ^ 1];
        unsigned short* BsN = Bs[(t & 1) ^ 1];
        float4 av[4];
        if (t < 7) {
            int k1 = (t + 1) * BK;
            // issue next A-tile HBM loads (latency hidden under MFMA below)
            #pragma unroll
            for (int it = 0; it < 4; ++it) {
                int idx = it * 512 + tid;
                int row = idx >> 4, c4 = idx & 15;
                av[it] = *(const float4*)(Abase + (size_t)row * DD + k1 + c4 * 4);
            }
            // issue next B-tile gload_lds into the alternate buffer
            #pragma unroll
            for (int u = 0; u < 8; ++u) {
                int n0 = w * 64 + u * 8;
                gload_lds16(Bt + (size_t)(n0 + rl) * DD + k1 + ((gg ^ rl) << 3),
                            &BsN[n0 * 64]);
            }
        }
        __builtin_amdgcn_s_setprio(1);
        #pragma unroll
        for (int ks = 0; ks < BK; ks += 32) {
            int gk = ks >> 3;  // 0 or 4
            s16x8 af[4], bfr[8];
            #pragma unroll
            for (int i = 0; i < 4; ++i) {
                int row = wm + i * 16 + lcol, g = gk + q;
                af[i] = *(const s16x8*)&AsC[(g * 128 + (row ^ g)) * 8];
            }
            #pragma unroll
            for (int j = 0; j < 8; ++j) {
                int col = wn + j * 16 + lcol, g = gk + q;
                bfr[j] = *(const s16x8*)&BsC[col * 64 + ((g ^ (col & 7)) << 3)];
            }
            #pragma unroll
            for (int i = 0; i < 4; ++i)
                #pragma unroll
                for (int j = 0; j < 8; ++j)
                    acc[i][j] = __builtin_amdgcn_mfma_f32_16x16x32_bf16(
                        af[i], bfr[j], acc[i][j], 0, 0, 0);
        }
        __builtin_amdgcn_s_setprio(0);
        __builtin_amdgcn_sched_barrier(0);   // keep the pack AFTER the MFMAs
        if (t < 7) {
            #pragma unroll
            for (int it = 0; it < 4; ++it) {
                int idx = it * 512 + tid;
                int row = idx >> 4, c4 = idx & 15;
                uint2 wv;
                wv.x = pack_bf16_trunc(av[it].x, av[it].y);
                wv.y = pack_bf16_trunc(av[it].z, av[it].w);
                int g = c4 >> 1, half = c4 & 1;
                *(uint2*)&AsN[(g * 128 + (row ^ g)) * 8 + half * 4] = wv;
            }
        }
        __syncthreads();
    }

    // Epilogue: per (i,r) row-partial over this wave's 128 cols; 4-way wc
    // reduce in LDS (reusing As space), then direct cij store.
    // C/D layout: col = lane&15, row = (lane>>4)*4 + reg
    int b = m0 >> 12;
    float cvv[8], Vv[8];
    #pragma unroll
    for (int j = 0; j < 8; ++j) {
        int h = wn + j * 16 + lcol;
        cvv[j] = cvec[b * HH + h];
        Vv[j] = V[h];
    }
    float* redf = (float*)As;   // 128 rows x 4 wc = 2 KB, As is dead now
    #pragma unroll
    for (int i = 0; i < 4; ++i) {
        #pragma unroll
        for (int r = 0; r < 4; ++r) {
            float s = 0.0f;
            #pragma unroll
            for (int j = 0; j < 8; ++j)
                s = fmaf(tanh_fast(acc[i][j][r] + cvv[j]), Vv[j], s);
            s += __shfl_xor(s, 1);
            s += __shfl_xor(s, 2);
            s += __shfl_xor(s, 4);
            s += __shfl_xor(s, 8);
            if (lcol == 0)
                redf[(wm + i * 16 + q * 4 + r) * 4 + wc] = s;
        }
    }
    __syncthreads();
    if (tid < 128) {
        float v = redf[tid * 4] + redf[tid * 4 + 1] +
                  redf[tid * 4 + 2] + redf[tid * 4 + 3];
        cij[m0 + tid] = v;
    }
}

// ---------------------------------------------------------------------------
// C1: per-b softmax stats only: smst[b] = (max, 1/sum). alphas are produced
// inline by k_wsum (saves a full 1MB read+write pass).
__global__ void k_smstats(const float* __restrict__ cij, float* __restrict__ smst) {
    int b = blockIdx.x, tid = threadIdx.x;
    const float* row = cij + (size_t)b * TT;
    __shared__ float red[4];
    float m = -1e30f;
    for (int t = tid; t < TT; t += 256) m = fmaxf(m, row[t]);
    #pragma unroll
    for (int o = 1; o < 64; o <<= 1) m = fmaxf(m, __shfl_xor(m, o));
    if ((tid & 63) == 0) red[tid >> 6] = m;
    __syncthreads();
    m = fmaxf(fmaxf(red[0], red[1]), fmaxf(red[2], red[3]));
    __syncthreads();
    float sum = 0.0f;
    for (int t = tid; t < TT; t += 256) sum += __expf(row[t] - m);
    #pragma unroll
    for (int o = 1; o < 64; o <<= 1) sum += __shfl_xor(sum, o);
    if ((tid & 63) == 0) red[tid >> 6] = sum;
    __syncthreads();
    if (tid == 0) {
        smst[b * 2] = m;
        smst[b * 2 + 1] = 1.0f / (red[0] + red[1] + red[2] + red[3]);
    }
}

// C2a: partial weighted sums, NO atomics; alphas computed inline from cij and
// written out here. Block mapping REVERSED so the first-dispatched blocks read
// the tail of e, which the GEMM just left resident in the 256MB L3.
__global__ void k_wsum(const float* __restrict__ e, const float* __restrict__ cij,
                       const float* __restrict__ smst, float* __restrict__ alphas,
                       float* __restrict__ pw) {
    int bc = (BB * 64 - 1) - blockIdx.x;
    int b = bc >> 6;
    int chunk = bc & 63;
    int t0 = chunk * 64;
    int tid = threadIdx.x;
    float m = smst[b * 2], inv = smst[b * 2 + 1];
    const float* crow = cij + (size_t)b * TT;
    if (tid < 64)
        alphas[(size_t)b * TT + t0 + tid] = __expf(crow[t0 + tid] - m) * inv;
    int half = tid >> 7, f4 = tid & 127;
    const float* base = e + (size_t)b * TT * DD;
    f32x4 a0 = {0, 0, 0, 0}, a1 = {0, 0, 0, 0};
    for (int it = 0; it < 16; ++it) {
        int t = t0 + it * 4 + half;
        float w0 = __expf(crow[t] - m) * inv;
        float w1 = __expf(crow[t + 2] - m) * inv;
        f32x4 v0 = *(const f32x4*)(base + (size_t)t * DD + f4 * 4);
        f32x4 v1 = *(const f32x4*)(base + (size_t)(t + 2) * DD + f4 * 4);
        a0 += w0 * v0;
        a1 += w1 * v1;
    }
    a0 += a1;
    __shared__ f32x4 red[128];
    if (half == 1) red[f4] = a0;
    __syncthreads();
    if (half == 0) {
        a0 += red[f4];
        *(f32x4*)&pw[((size_t)(b * 64 + chunk)) * DD + f4 * 4] = a0;
    }
}

// C2b: out[b,d] = sum_chunk pw[b][chunk][d]. 4MB read, trivial.
__global__ void k_wred(const float* __restrict__ pw, float* __restrict__ out) {
    int b = blockIdx.x, tid = threadIdx.x;
    float2 acc = {0.0f, 0.0f};
    const float* base = pw + (size_t)b * 64 * DD;
    #pragma unroll 4
    for (int c = 0; c < 64; ++c) {
        float2 v = *(const float2*)(base + (size_t)c * DD + tid * 2);
        acc.x += v.x;
        acc.y += v.y;
    }
    *(float2*)&out[b * DD + tid * 2] = acc;
}

// ---------------------------------------------------------------------------
extern "C" void kernel_launch(void* const* d_in, const int* in_sizes, int n_in,
                              void* d_out, int out_size, void* d_ws, size_t ws_size,
                              hipStream_t stream) {
    const float* hs   = (const float*)d_in[0];   // [32,512]
    const float* e    = (const float*)d_in[1];   // [32,4096,512]
    const float* W    = (const float*)d_in[2];   // [512,512]
    const float* U    = (const float*)d_in[3];   // [512,512]
    const float* V    = (const float*)d_in[4];   // [512]
    const float* bias = (const float*)d_in[5];   // [512]
    const float* Wa   = (const float*)d_in[6];   // [512,512]
    const float* ba   = (const float*)d_in[7];   // [512]

    float* out    = (float*)d_out;               // [32,512] then alphas [32,4096]
    float* alphas = out + BB * DD;

    float*          cij  = (float*)d_ws;                              // 512 KB
    float*          cvec = (float*)((char*)d_ws + 524288);            // 64 KB
    float*          smst = (float*)((char*)d_ws + 589824);            // 256 B
    unsigned short* Bt   = (unsigned short*)((char*)d_ws + 593920);   // 512 KB bf16
    float*          pw   = (float*)((char*)d_ws + 1179648);           // 4 MB

    k_head<<<BB, 256, 0, stream>>>(hs, W, bias, Wa, ba, cvec);
    k_uwa<<<64, 256, 0, stream>>>(U, Wa, Bt);
    k_gemm_tanh<<<1024, 512, 0, stream>>>(e, Bt, cvec, V, cij);
    k_smstats<<<BB, 256, 0, stream>>>(cij, smst);
    k_wsum<<<BB * 64, 256, 0, stream>>>(e, cij, smst, alphas, pw);
    k_wred<<<BB, 256, 0, stream>>>(pw, out);
}

// Round 3
// 516.031 us; speedup vs baseline: 1.1188x; 1.1188x over previous
//
#include <hip/hip_runtime.h>
#include <hip/hip_bf16.h>

// Bahdanau attention, restructured:
//   tanh_in[b,t,k] = e[b,t,:]@(U@Wa) + cvec[b,k]   (one 131072x512x512 bf16 GEMM)
//   cij[b,t] = sum_k tanh(tanh_in)*V[k]            (fused epilogue)
//   alphas = softmax(cij); out = sum_t alphas*e
// Shapes: B=32 T=4096 D=512 H=512.
//
// R6: flash-style fusion of the weighted sum INTO the GEMM epilogue.
// Each GEMM block (128 t-rows of one b) computes chunk stats (m_c, Z_c) and
// the unnormalized partial sum pw~[d] = sum_t exp(cij_t - m_c) * e[t,d],
// re-reading its own 128 e-rows from L2/L3 (just streamed, hot). k_final
// (32 blocks) combines chunks with exact exp(m_c - M) rescaling -> out, and
// emits alphas from cij. This deletes k_smstats/k_wsum/k_wred and the second
// 256 MiB HBM pass over e. k_head+k_uwa merged into one 96-block dispatch.
// GEMM core reverted to the proven single-buffer R4 loop (dbuf was -8us).
// Pipeline: 3 dispatches, no atomics, no memset.

#define BB 32
#define TT 4096
#define DD 512
#define HH 512
#define BK 64

typedef short s16x8 __attribute__((ext_vector_type(8)));
typedef float f32x4 __attribute__((ext_vector_type(4)));

union FU { float f; unsigned u; };

static __device__ __forceinline__ unsigned pack_bf16_trunc(float a, float b) {
    FU ua, ub; ua.f = a; ub.f = b;
    return (ua.u >> 16) | (ub.u & 0xffff0000u);
}

static __device__ __forceinline__ unsigned short f2bf_rne(float x) {
    FU v; v.f = x;
    unsigned u = v.u;
    u = u + 0x7fffu + ((u >> 16) & 1u);
    return (unsigned short)(u >> 16);
}

static __device__ __forceinline__ float tanh_fast(float x) {
    float e = __expf(2.0f * x);
    return 1.0f - 2.0f * __builtin_amdgcn_rcpf(e + 1.0f);
}

// async global->LDS, 16B/lane. LDS dest = wave-uniform base + lane*16.
static __device__ __forceinline__ void gload_lds16(const void* g, void* l) {
    __builtin_amdgcn_global_load_lds(
        (const __attribute__((address_space(1))) unsigned int*)g,
        (__attribute__((address_space(3))) unsigned int*)l, 16, 0, 0);
}

// ---------------------------------------------------------------------------
// k_pre: blocks 0..63 compute UWaT (A3); blocks 64..95 compute cvec (A1+A2
// fused). One dispatch instead of two serialized underfilling launches.
__global__ void k_pre(const float* __restrict__ U, const float* __restrict__ Wa,
                      unsigned short* __restrict__ UWaT,
                      const float* __restrict__ hs, const float* __restrict__ W,
                      const float* __restrict__ bias, const float* __restrict__ ba,
                      float* __restrict__ cvec) {
    __shared__ float smem[8 * DD];   // 16 KB, reused by both paths
    int tid = threadIdx.x;
    if (blockIdx.x < 64) {
        // ---- UWaT[n][d] = bf16( sum_h U[d,h]*Wa[h,n] ), 8 d-rows per block
        int d0 = blockIdx.x * 8;
        float (*Us)[DD] = (float(*)[DD])smem;
        #pragma unroll
        for (int i = 0; i < 16; ++i) {
            int idx = i * 256 + tid;
            Us[idx >> 9][idx & 511] = U[(size_t)(d0 + (idx >> 9)) * HH + (idx & 511)];
        }
        __syncthreads();
        float acc[8][2] = {};
        #pragma unroll 2
        for (int h = 0; h < DD; ++h) {
            float w0 = Wa[(size_t)h * HH + tid];
            float w1 = Wa[(size_t)h * HH + 256 + tid];
            #pragma unroll
            for (int dd = 0; dd < 8; ++dd) {
                float u = Us[dd][h];
                acc[dd][0] = fmaf(u, w0, acc[dd][0]);
                acc[dd][1] = fmaf(u, w1, acc[dd][1]);
            }
        }
        #pragma unroll
        for (int dd = 0; dd < 8; ++dd) {
            UWaT[(size_t)tid * DD + d0 + dd] = f2bf_rne(acc[dd][0]);
            UWaT[(size_t)(tid + 256) * DD + d0 + dd] = f2bf_rne(acc[dd][1]);
        }
    } else {
        // ---- g = hs@W + bias (LDS), cvec = g@Wa + ba (direct store)
        int b = blockIdx.x - 64;
        float* hss = smem;            // 512
        float* gs = smem + DD;        // 512
        if (tid < 128)
            ((float4*)hss)[tid] = ((const float4*)(hs + (size_t)b * DD))[tid];
        __syncthreads();
        float a0 = bias[tid], a1 = bias[tid + 256];
        #pragma unroll 8
        for (int d = 0; d < DD; ++d) {
            float x = hss[d];
            a0 = fmaf(x, W[(size_t)d * HH + tid], a0);
            a1 = fmaf(x, W[(size_t)d * HH + 256 + tid], a1);
        }
        gs[tid] = a0;
        gs[tid + 256] = a1;
        __syncthreads();
        float c0 = ba[tid], c1 = ba[tid + 256];
        #pragma unroll 8
        for (int h = 0; h < HH; ++h) {
            float x = gs[h];
            c0 = fmaf(x, Wa[(size_t)h * HH + tid], c0);
            c1 = fmaf(x, Wa[(size_t)h * HH + 256 + tid], c1);
        }
        cvec[(size_t)b * HH + tid] = c0;
        cvec[(size_t)b * HH + 256 + tid] = c1;
    }
}

// ---------------------------------------------------------------------------
// B: GEMM tile 128(M) x 512(N full), BK=64, single-buffer (proven R4 loop).
// 8 waves (2x4): wave (wr,wc) owns rows [wr*64,+64) x cols [wc*128,+128).
// LDS 16B-unit layouts (verified conflict-free):
//   Bs unit = col*8 + (g ^ (col&7)) ; As unit = g*128 + (row ^ g)
// Epilogue (new): cross-wave cij reduce -> chunk softmax stats (m_c, Z_c) ->
// unnormalized pw~[d] = sum_{128 t} exp(cij_t - m_c) * e[t,d] with e re-read
// from L2/L3 (rows just streamed by this block). No atomics anywhere.
__global__ void __launch_bounds__(512, 2) k_gemm_tanh(
    const float* __restrict__ e, const unsigned short* __restrict__ Bt,
    const float* __restrict__ cvec, const float* __restrict__ V,
    float* __restrict__ cij, float* __restrict__ pw, float* __restrict__ mz) {
    int tid = threadIdx.x;
    int m0 = blockIdx.x * 128;         // 1024 blocks
    int lane = tid & 63, w = tid >> 6;
    int wr = w >> 2, wc = w & 3;
    int wm = wr * 64, wn = wc * 128;
    int lcol = lane & 15, q = lane >> 4;
    int rl = lane >> 3, gg = lane & 7;           // staging lane decomposition

    __shared__ __align__(16) unsigned short As[128 * BK];   // 16 KB
    __shared__ __align__(16) unsigned short Bs[512 * BK];   // 64 KB
    __shared__ float red2[4];

    f32x4 acc[4][8] = {};
    const float* Abase = e + (size_t)m0 * DD;

    for (int k0 = 0; k0 < DD; k0 += BK) {
        // A: issue the 4 HBM float4 loads first (longest latency).
        float4 av[4];
        #pragma unroll
        for (int it = 0; it < 4; ++it) {
            int idx = it * 512 + tid;
            int row = idx >> 4, c4 = idx & 15;
            av[it] = *(const float4*)(Abase + (size_t)row * DD + k0 + c4 * 4);
        }
        // B: 8 coalesced global_load_lds per wave; wave w stages rows [w*64,+64).
        #pragma unroll
        for (int u = 0; u < 8; ++u) {
            int n0 = w * 64 + u * 8;
            gload_lds16(Bt + (size_t)(n0 + rl) * DD + k0 + ((gg ^ rl) << 3),
                        &Bs[n0 * 64]);
        }
        // A: convert + swizzled ds_write.
        #pragma unroll
        for (int it = 0; it < 4; ++it) {
            int idx = it * 512 + tid;
            int row = idx >> 4, c4 = idx & 15;
            uint2 wv;
            wv.x = pack_bf16_trunc(av[it].x, av[it].y);
            wv.y = pack_bf16_trunc(av[it].z, av[it].w);
            int g = c4 >> 1, half = c4 & 1;
            *(uint2*)&As[(g * 128 + (row ^ g)) * 8 + half * 4] = wv;
        }
        __syncthreads();
        #pragma unroll
        for (int ks = 0; ks < BK; ks += 32) {
            int gk = ks >> 3;  // 0 or 4
            s16x8 af[4], bfr[8];
            #pragma unroll
            for (int i = 0; i < 4; ++i) {
                int row = wm + i * 16 + lcol, g = gk + q;
                af[i] = *(const s16x8*)&As[(g * 128 + (row ^ g)) * 8];
            }
            #pragma unroll
            for (int j = 0; j < 8; ++j) {
                int col = wn + j * 16 + lcol, g = gk + q;
                bfr[j] = *(const s16x8*)&Bs[col * 64 + ((g ^ (col & 7)) << 3)];
            }
            #pragma unroll
            for (int i = 0; i < 4; ++i)
                #pragma unroll
                for (int j = 0; j < 8; ++j)
                    acc[i][j] = __builtin_amdgcn_mfma_f32_16x16x32_bf16(
                        af[i], bfr[j], acc[i][j], 0, 0, 0);
        }
        __syncthreads();
    }

    // ---- Epilogue 1: per-row cij via tanh/V dot + 4-way wc reduce in LDS.
    // C/D layout: col = lane&15, row = (lane>>4)*4 + reg
    int b = m0 >> 12;
    float cvv[8], Vv[8];
    #pragma unroll
    for (int j = 0; j < 8; ++j) {
        int h = wn + j * 16 + lcol;
        cvv[j] = cvec[b * HH + h];
        Vv[j] = V[h];
    }
    float* redf = (float*)As;    // 128 rows x 4 wc = 2 KB (As dead)
    float* wbuf = (float*)Bs;    // 128 exp weights (Bs dead)
    #pragma unroll
    for (int i = 0; i < 4; ++i) {
        #pragma unroll
        for (int r = 0; r < 4; ++r) {
            float s = 0.0f;
            #pragma unroll
            for (int j = 0; j < 8; ++j)
                s = fmaf(tanh_fast(acc[i][j][r] + cvv[j]), Vv[j], s);
            s += __shfl_xor(s, 1);
            s += __shfl_xor(s, 2);
            s += __shfl_xor(s, 4);
            s += __shfl_xor(s, 8);
            if (lcol == 0)
                redf[(wm + i * 16 + q * 4 + r) * 4 + wc] = s;
        }
    }
    __syncthreads();

    // ---- Epilogue 2: chunk stats + exp weights (waves 0-1 own the 128 rows).
    float v = 0.0f;
    if (tid < 128) {
        v = redf[tid * 4] + redf[tid * 4 + 1] + redf[tid * 4 + 2] + redf[tid * 4 + 3];
        cij[m0 + tid] = v;
        float mm = v;
        #pragma unroll
        for (int o = 1; o < 64; o <<= 1) mm = fmaxf(mm, __shfl_xor(mm, o));
        if (lane == 0) red2[tid >> 6] = mm;
    }
    __syncthreads();
    float m_c = fmaxf(red2[0], red2[1]);
    if (tid < 128) {
        float wv = __expf(v - m_c);
        wbuf[tid] = wv;
        float ss = wv;
        #pragma unroll
        for (int o = 1; o < 64; o <<= 1) ss += __shfl_xor(ss, o);
        if (lane == 0) red2[2 + (tid >> 6)] = ss;
    }
    __syncthreads();
    if (tid == 0) {
        mz[blockIdx.x * 2] = m_c;
        mz[blockIdx.x * 2 + 1] = red2[2] + red2[3];
    }

    // ---- Epilogue 3: pw~[d] = sum_t wbuf[t] * e[m0+t, d]; rows are L2/L3-hot.
    // 512 threads = full d range; per-iteration the block reads one contiguous
    // 2 KB row (coalesced); wbuf[t] is a same-address LDS broadcast.
    float pacc = 0.0f;
    const float* ecol = e + (size_t)m0 * DD + tid;
    #pragma unroll 8
    for (int t = 0; t < 128; ++t)
        pacc = fmaf(wbuf[t], ecol[(size_t)t * DD], pacc);
    pw[(size_t)blockIdx.x * DD + tid] = pacc;
}

// ---------------------------------------------------------------------------
// k_final: one block per b. Combine 32 chunks with exact rescaling:
//   M = max_c m_c ; Z = sum_c exp(m_c-M)*Z_c
//   out[b,d] = (1/Z) * sum_c exp(m_c-M) * pw~[b,c,d]
//   alphas[b,t] = exp(cij[b,t]-M)/Z
__global__ void k_final(const float* __restrict__ cij, const float* __restrict__ pw,
                        const float* __restrict__ mz, float* __restrict__ alphas,
                        float* __restrict__ out) {
    int b = blockIdx.x, tid = threadIdx.x;   // 256 threads
    __shared__ float ef[32];
    __shared__ float red[2];
    float m = (tid < 32) ? mz[(size_t)(b * 32 + tid) * 2] : -1e30f;
    if (tid < 64) {
        #pragma unroll
        for (int o = 1; o < 64; o <<= 1) m = fmaxf(m, __shfl_xor(m, o));
        if (tid == 0) red[0] = m;
    }
    __syncthreads();
    float M = red[0];
    if (tid < 64) {
        float z = 0.0f;
        if (tid < 32) {
            float e_ = __expf(mz[(size_t)(b * 32 + tid) * 2] - M);
            ef[tid] = e_;
            z = e_ * mz[(size_t)(b * 32 + tid) * 2 + 1];
        }
        #pragma unroll
        for (int o = 1; o < 64; o <<= 1) z += __shfl_xor(z, o);
        if (tid == 0) red[1] = z;
    }
    __syncthreads();
    float inv = 1.0f / red[1];
    #pragma unroll
    for (int d = tid; d < DD; d += 256) {
        float s = 0.0f;
        #pragma unroll 8
        for (int c = 0; c < 32; ++c)
            s = fmaf(ef[c], pw[(size_t)(b * 32 + c) * DD + d], s);
        out[(size_t)b * DD + d] = s * inv;
    }
    const float* crow = cij + (size_t)b * TT;
    for (int t = tid; t < TT; t += 256)
        alphas[(size_t)b * TT + t] = __expf(crow[t] - M) * inv;
}

// ---------------------------------------------------------------------------
extern "C" void kernel_launch(void* const* d_in, const int* in_sizes, int n_in,
                              void* d_out, int out_size, void* d_ws, size_t ws_size,
                              hipStream_t stream) {
    const float* hs   = (const float*)d_in[0];   // [32,512]
    const float* e    = (const float*)d_in[1];   // [32,4096,512]
    const float* W    = (const float*)d_in[2];   // [512,512]
    const float* U    = (const float*)d_in[3];   // [512,512]
    const float* V    = (const float*)d_in[4];   // [512]
    const float* bias = (const float*)d_in[5];   // [512]
    const float* Wa   = (const float*)d_in[6];   // [512,512]
    const float* ba   = (const float*)d_in[7];   // [512]

    float* out    = (float*)d_out;               // [32,512] then alphas [32,4096]
    float* alphas = out + BB * DD;

    float*          cij  = (float*)d_ws;                              // 512 KB
    float*          cvec = (float*)((char*)d_ws + 524288);            // 64 KB
    unsigned short* Bt   = (unsigned short*)((char*)d_ws + 589824);   // 512 KB bf16
    float*          mz   = (float*)((char*)d_ws + 1114112);           // 8 KB
    float*          pw   = (float*)((char*)d_ws + 1122304);           // 2 MB

    k_pre<<<96, 256, 0, stream>>>(U, Wa, Bt, hs, W, bias, ba, cvec);
    k_gemm_tanh<<<1024, 512, 0, stream>>>(e, Bt, cvec, V, cij, pw, mz);
    k_final<<<BB, 256, 0, stream>>>(cij, pw, mz, alphas, out);
}